// Round 1
// baseline (244.623 us; speedup 1.0000x reference)
//
#include <hip/hip_runtime.h>
#include <cstdint>
#include <cstddef>

#define DMAX 8732
#define JT 0.5f

__device__ __forceinline__ float sl1(float d) {
    float ad = fabsf(d);
    return (ad < 1.0f) ? 0.5f * d * d : ad - 0.5f;
}

// ---------------- Kernel A: per-batch matching ----------------
template<int TT>
__global__ __launch_bounds__(256) void match_kernel(
    const float* __restrict__ loc, const float* __restrict__ dbox,
    const float* __restrict__ targets, int D,
    int* __restrict__ conf_t, int* __restrict__ num_pos,
    float* __restrict__ loss_l_part, float* __restrict__ posce)
{
    const int b = blockIdx.x;
    const int tid = threadIdx.x;

    __shared__ float s_tr[TT][4];
    __shared__ float s_area[TT];
    __shared__ int   s_lab[TT];
    __shared__ unsigned long long s_bpkey[TT];
    __shared__ float s_btov[DMAX];
    __shared__ unsigned short s_btidx[DMAX];
    __shared__ float s_rf[4];
    __shared__ int   s_ri[4];

    if (tid < TT) {
        const float* tg = targets + ((size_t)b * TT + tid) * 5;
        float x1 = tg[0], y1 = tg[1], x2 = tg[2], y2 = tg[3];
        s_tr[tid][0] = x1; s_tr[tid][1] = y1; s_tr[tid][2] = x2; s_tr[tid][3] = y2;
        s_area[tid] = (x2 - x1) * (y2 - y1);
        s_lab[tid] = (int)tg[4];
        s_bpkey[tid] = 0ull;
    }
    __syncthreads();

    unsigned long long lkey[TT];
#pragma unroll
    for (int t = 0; t < TT; ++t) lkey[t] = 0ull;

    for (int d = tid; d < D; d += blockDim.x) {
        float4 db = ((const float4*)dbox)[d];
        float dx1 = db.x - db.z * 0.5f, dy1 = db.y - db.w * 0.5f;
        float dx2 = db.x + db.z * 0.5f, dy2 = db.y + db.w * 0.5f;
        float area_d = (dx2 - dx1) * (dy2 - dy1);
        float best = -1.0f; int bi = 0;
#pragma unroll
        for (int t = 0; t < TT; ++t) {
            float lx = fmaxf(s_tr[t][0], dx1);
            float ly = fmaxf(s_tr[t][1], dy1);
            float rx = fminf(s_tr[t][2], dx2);
            float ry = fminf(s_tr[t][3], dy2);
            float w = fmaxf(rx - lx, 0.0f), h = fmaxf(ry - ly, 0.0f);
            float inter = w * h;
            float iou = inter / (s_area[t] + area_d - inter);
            if (iou > best) { best = iou; bi = t; }   // strict >: first-max (argmax over t)
            unsigned long long key =
                ((unsigned long long)__float_as_uint(iou) << 32) | (unsigned)(~(unsigned)d);
            if (key > lkey[t]) lkey[t] = key;         // max-value, min-index tie-break
        }
        s_btov[d] = best;
        s_btidx[d] = (unsigned short)bi;
    }
#pragma unroll
    for (int t = 0; t < TT; ++t) atomicMax(&s_bpkey[t], lkey[t]);
    __syncthreads();

    if (tid == 0) {
        // forcing: overlap=2.0 at each best prior; idx loop sequential (last j wins)
#pragma unroll
        for (int t = 0; t < TT; ++t) {
            unsigned d = ~(unsigned)(s_bpkey[t] & 0xFFFFFFFFu);
            if (d < (unsigned)D) {
                s_btov[d] = 2.0f;
                s_btidx[d] = (unsigned short)t;
            }
        }
    }
    __syncthreads();

    int local_pos = 0;
    float local_l1 = 0.0f;
    for (int d = tid; d < D; d += blockDim.x) {
        float ov = s_btov[d];
        int ti = s_btidx[d];
        int c = (ov < JT) ? 0 : (s_lab[ti] + 1);
        conf_t[(size_t)b * D + d] = c;
        if (c > 0) {
            ++local_pos;
            float4 db = ((const float4*)dbox)[d];
            float tx1 = s_tr[ti][0], ty1 = s_tr[ti][1], tx2 = s_tr[ti][2], ty2 = s_tr[ti][3];
            float mcx = (tx1 + tx2) * 0.5f, mcy = (ty1 + ty2) * 0.5f;
            float mw = tx2 - tx1, mh = ty2 - ty1;
            float gx = (mcx - db.x) / (0.1f * db.z);
            float gy = (mcy - db.y) / (0.1f * db.w);
            float gw = logf(mw / db.z) / 0.2f;
            float gh = logf(mh / db.w) / 0.2f;
            float4 lv = ((const float4*)loc)[(size_t)b * D + d];
            local_l1 += sl1(lv.x - gx) + sl1(lv.y - gy) + sl1(lv.z - gw) + sl1(lv.w - gh);
        }
    }

    for (int o = 32; o; o >>= 1) {
        local_l1 += __shfl_down(local_l1, o);
        local_pos += __shfl_down(local_pos, o);
    }
    int wv = tid >> 6;
    if ((tid & 63) == 0) { s_rf[wv] = local_l1; s_ri[wv] = local_pos; }
    __syncthreads();
    if (tid == 0) {
        float L = 0.0f; int P = 0;
        for (int w = 0; w < 4; ++w) { L += s_rf[w]; P += s_ri[w]; }
        loss_l_part[b] = L;
        num_pos[b] = P;
        posce[b] = 0.0f;
    }
}

// ---------------- Kernel B: CE per (b,d) row (wave per row) ----------------
__global__ __launch_bounds__(256) void ce_kernel(
    const float* __restrict__ conf, const int* __restrict__ conf_t,
    int D, int C,
    float* __restrict__ lossc, float* __restrict__ posce)
{
    const int b = blockIdx.y;
    const int wv = blockIdx.x * (blockDim.x >> 6) + (threadIdx.x >> 6);
    const int nwv = gridDim.x * (blockDim.x >> 6);
    const int lane = threadIdx.x & 63;

    for (int d = wv; d < D; d += nwv) {
        size_t row = (size_t)b * D + d;
        const float* x = conf + row * (size_t)C;
        float x0 = x[lane];
        bool has2 = (lane + 64) < C;
        float x1 = has2 ? x[lane + 64] : -INFINITY;
        float m = fmaxf(x0, x1);
        for (int o = 32; o; o >>= 1) m = fmaxf(m, __shfl_xor(m, o));
        float s = __expf(x0 - m) + (has2 ? __expf(x1 - m) : 0.0f);
        for (int o = 32; o; o >>= 1) s += __shfl_xor(s, o);
        if (lane == 0) {
            int c = conf_t[row];
            float lse = m + __logf(s);
            float ce = lse - x[c];
            lossc[row] = (c > 0) ? 0.0f : ce;
            if (c > 0) atomicAdd(&posce[b], ce);
        }
    }
}

// ---------------- Kernel C: hard negative mining via bit-bisection select ----------------
__global__ __launch_bounds__(256) void hnm_kernel(
    const float* __restrict__ lossc, const int* __restrict__ num_pos,
    const float* __restrict__ posce, int D,
    float* __restrict__ hnm)
{
    const int b = blockIdx.x;
    const int tid = threadIdx.x;
    __shared__ unsigned s_bits[DMAX];
    __shared__ int s_cnt[4];
    __shared__ float s_sf[4];

    for (int d = tid; d < D; d += blockDim.x)
        s_bits[d] = __float_as_uint(lossc[(size_t)b * D + d]);
    const int k = min(num_pos[b] * 3, D);
    __syncthreads();

    // largest uint T with count(bits >= T) >= k  ->  T = bits of k-th largest value
    unsigned T = 0;
    for (int bit = 30; bit >= 0; --bit) {   // values are finite non-negative floats: bit31=0
        unsigned cand = T | (1u << bit);
        int cnt = 0;
        for (int d = tid; d < D; d += blockDim.x) cnt += (s_bits[d] >= cand) ? 1 : 0;
        for (int o = 32; o; o >>= 1) cnt += __shfl_down(cnt, o);
        if ((tid & 63) == 0) s_cnt[tid >> 6] = cnt;
        __syncthreads();
        int tot = s_cnt[0] + s_cnt[1] + s_cnt[2] + s_cnt[3];
        if (tot >= k) T = cand;
        __syncthreads();
    }

    // sum of top-k values = sum(v > Vk) + (k - count(v > Vk)) * Vk   (tie-agnostic)
    int cgt = 0; float sgt = 0.0f;
    for (int d = tid; d < D; d += blockDim.x) {
        unsigned v = s_bits[d];
        if (v > T) { ++cgt; sgt += __uint_as_float(v); }
    }
    for (int o = 32; o; o >>= 1) { cgt += __shfl_down(cgt, o); sgt += __shfl_down(sgt, o); }
    if ((tid & 63) == 0) { s_cnt[tid >> 6] = cgt; s_sf[tid >> 6] = sgt; }
    __syncthreads();
    if (tid == 0) {
        int C_gt = s_cnt[0] + s_cnt[1] + s_cnt[2] + s_cnt[3];
        float S_gt = s_sf[0] + s_sf[1] + s_sf[2] + s_sf[3];
        hnm[b] = posce[b] + S_gt + (float)(k - C_gt) * __uint_as_float(T);
    }
}

// ---------------- Kernel D: finalize ----------------
__global__ void finalize_kernel(
    const int* __restrict__ num_pos, const float* __restrict__ loss_l_part,
    const float* __restrict__ hnm, int B, float* __restrict__ out)
{
    int lane = threadIdx.x;
    int np = 0; float ll = 0.0f, lc = 0.0f;
    for (int b = lane; b < B; b += 64) {
        np += num_pos[b]; ll += loss_l_part[b]; lc += hnm[b];
    }
    for (int o = 32; o; o >>= 1) {
        np += __shfl_down(np, o); ll += __shfl_down(ll, o); lc += __shfl_down(lc, o);
    }
    if (lane == 0) {
        float N = (float)np;
        out[0] = ll / N;
        out[1] = lc / N;
    }
}

extern "C" void kernel_launch(void* const* d_in, const int* in_sizes, int n_in,
                              void* d_out, int out_size, void* d_ws, size_t ws_size,
                              hipStream_t stream) {
    const float* loc     = (const float*)d_in[0];
    const float* conf    = (const float*)d_in[1];
    const float* dbox    = (const float*)d_in[2];
    const float* targets = (const float*)d_in[3];

    const int D = in_sizes[2] / 4;               // 8732
    const int B = in_sizes[0] / (D * 4);         // 64
    const int C = in_sizes[1] / (B * D);         // 81

    char* p = (char*)d_ws;
    int*   conf_t      = (int*)p;   p += (size_t)B * D * sizeof(int);
    float* lossc       = (float*)p; p += (size_t)B * D * sizeof(float);
    int*   num_pos     = (int*)p;   p += (size_t)B * sizeof(int);
    float* loss_l_part = (float*)p; p += (size_t)B * sizeof(float);
    float* posce       = (float*)p; p += (size_t)B * sizeof(float);
    float* hnm         = (float*)p; p += (size_t)B * sizeof(float);

    match_kernel<8><<<B, 256, 0, stream>>>(loc, dbox, targets, D,
                                           conf_t, num_pos, loss_l_part, posce);
    ce_kernel<<<dim3(32, B), 256, 0, stream>>>(conf, conf_t, D, C, lossc, posce);
    hnm_kernel<<<B, 256, 0, stream>>>(lossc, num_pos, posce, D, hnm);
    finalize_kernel<<<1, 64, 0, stream>>>(num_pos, loss_l_part, hnm, B, (float*)d_out);
}

// Round 2
// 204.864 us; speedup vs baseline: 1.1941x; 1.1941x over previous
//
#include <hip/hip_runtime.h>
#include <cstdint>
#include <cstddef>

#define DMAX 8732
#define JT 0.5f

__device__ __forceinline__ float sl1(float d) {
    float ad = fabsf(d);
    return (ad < 1.0f) ? 0.5f * d * d : ad - 0.5f;
}

// ---------------- Kernel A: per-batch matching ----------------
template<int TT>
__global__ __launch_bounds__(256) void match_kernel(
    const float* __restrict__ loc, const float* __restrict__ dbox,
    const float* __restrict__ targets, int D,
    int* __restrict__ conf_t, int* __restrict__ num_pos,
    float* __restrict__ loss_l_part, float* __restrict__ posce)
{
    const int b = blockIdx.x;
    const int tid = threadIdx.x;

    __shared__ float s_tr[TT][4];
    __shared__ float s_area[TT];
    __shared__ int   s_lab[TT];
    __shared__ unsigned long long s_bpkey[TT];
    __shared__ float s_btov[DMAX];
    __shared__ unsigned short s_btidx[DMAX];
    __shared__ float s_rf[4];
    __shared__ int   s_ri[4];

    if (tid < TT) {
        const float* tg = targets + ((size_t)b * TT + tid) * 5;
        float x1 = tg[0], y1 = tg[1], x2 = tg[2], y2 = tg[3];
        s_tr[tid][0] = x1; s_tr[tid][1] = y1; s_tr[tid][2] = x2; s_tr[tid][3] = y2;
        s_area[tid] = (x2 - x1) * (y2 - y1);
        s_lab[tid] = (int)tg[4];
        s_bpkey[tid] = 0ull;
    }
    __syncthreads();

    unsigned long long lkey[TT];
#pragma unroll
    for (int t = 0; t < TT; ++t) lkey[t] = 0ull;

    for (int d = tid; d < D; d += blockDim.x) {
        float4 db = ((const float4*)dbox)[d];
        float dx1 = db.x - db.z * 0.5f, dy1 = db.y - db.w * 0.5f;
        float dx2 = db.x + db.z * 0.5f, dy2 = db.y + db.w * 0.5f;
        float area_d = (dx2 - dx1) * (dy2 - dy1);
        float best = -1.0f; int bi = 0;
#pragma unroll
        for (int t = 0; t < TT; ++t) {
            float lx = fmaxf(s_tr[t][0], dx1);
            float ly = fmaxf(s_tr[t][1], dy1);
            float rx = fminf(s_tr[t][2], dx2);
            float ry = fminf(s_tr[t][3], dy2);
            float w = fmaxf(rx - lx, 0.0f), h = fmaxf(ry - ly, 0.0f);
            float inter = w * h;
            float iou = inter / (s_area[t] + area_d - inter);
            if (iou > best) { best = iou; bi = t; }   // strict >: first-max (argmax over t)
            unsigned long long key =
                ((unsigned long long)__float_as_uint(iou) << 32) | (unsigned)(~(unsigned)d);
            if (key > lkey[t]) lkey[t] = key;         // max-value, min-index tie-break
        }
        s_btov[d] = best;
        s_btidx[d] = (unsigned short)bi;
    }
#pragma unroll
    for (int t = 0; t < TT; ++t) atomicMax(&s_bpkey[t], lkey[t]);
    __syncthreads();

    if (tid == 0) {
        // forcing: overlap=2.0 at each best prior; idx loop sequential (last j wins)
#pragma unroll
        for (int t = 0; t < TT; ++t) {
            unsigned d = ~(unsigned)(s_bpkey[t] & 0xFFFFFFFFu);
            if (d < (unsigned)D) {
                s_btov[d] = 2.0f;
                s_btidx[d] = (unsigned short)t;
            }
        }
    }
    __syncthreads();

    int local_pos = 0;
    float local_l1 = 0.0f;
    for (int d = tid; d < D; d += blockDim.x) {
        float ov = s_btov[d];
        int ti = s_btidx[d];
        int c = (ov < JT) ? 0 : (s_lab[ti] + 1);
        conf_t[(size_t)b * D + d] = c;
        if (c > 0) {
            ++local_pos;
            float4 db = ((const float4*)dbox)[d];
            float tx1 = s_tr[ti][0], ty1 = s_tr[ti][1], tx2 = s_tr[ti][2], ty2 = s_tr[ti][3];
            float mcx = (tx1 + tx2) * 0.5f, mcy = (ty1 + ty2) * 0.5f;
            float mw = tx2 - tx1, mh = ty2 - ty1;
            float gx = (mcx - db.x) / (0.1f * db.z);
            float gy = (mcy - db.y) / (0.1f * db.w);
            float gw = logf(mw / db.z) / 0.2f;
            float gh = logf(mh / db.w) / 0.2f;
            float4 lv = ((const float4*)loc)[(size_t)b * D + d];
            local_l1 += sl1(lv.x - gx) + sl1(lv.y - gy) + sl1(lv.z - gw) + sl1(lv.w - gh);
        }
    }

    for (int o = 32; o; o >>= 1) {
        local_l1 += __shfl_down(local_l1, o);
        local_pos += __shfl_down(local_pos, o);
    }
    int wv = tid >> 6;
    if ((tid & 63) == 0) { s_rf[wv] = local_l1; s_ri[wv] = local_pos; }
    __syncthreads();
    if (tid == 0) {
        float L = 0.0f; int P = 0;
        for (int w = 0; w < 4; ++w) { L += s_rf[w]; P += s_ri[w]; }
        loss_l_part[b] = L;
        num_pos[b] = P;
        posce[b] = 0.0f;
    }
}

// ---------------- Kernel B: CE — quarter-wave (16 lanes) per row ----------------
__global__ __launch_bounds__(256) void ce_kernel(
    const float* __restrict__ conf, const int* __restrict__ conf_t,
    int D, int C,
    float* __restrict__ lossc, float* __restrict__ posce)
{
    const int b = blockIdx.y;
    const int lane = threadIdx.x & 63;
    const int sub = lane >> 4;          // quarter-wave 0..3
    const int l = lane & 15;            // lane within quarter-wave
    const int wv = blockIdx.x * (blockDim.x >> 6) + (threadIdx.x >> 6);
    const int nwv = gridDim.x * (blockDim.x >> 6);

    float pos_acc = 0.0f;

    for (int d0 = wv * 4; d0 < D; d0 += nwv * 4) {
        int d = d0 + sub;
        bool valid = d < D;
        size_t row = (size_t)b * D + (valid ? d : (D - 1));
        const float* x = conf + row * (size_t)C;

        // 6 stripes of 16 cover C<=96 (C=81)
        int i0 = l, i1 = l + 16, i2 = l + 32, i3 = l + 48, i4 = l + 64, i5 = l + 80;
        float v0 = x[i0];
        float v1 = x[i1];
        float v2 = x[i2];
        float v3 = x[i3];
        float v4 = (i4 < C) ? x[i4] : -INFINITY;
        float v5 = (i5 < C) ? x[i5] : -INFINITY;
        int c = conf_t[row];

        float m = fmaxf(fmaxf(fmaxf(v0, v1), fmaxf(v2, v3)), fmaxf(v4, v5));
#pragma unroll
        for (int o = 8; o; o >>= 1) m = fmaxf(m, __shfl_xor(m, o));

        float s = __expf(v0 - m) + __expf(v1 - m) + __expf(v2 - m) + __expf(v3 - m);
        if (i4 < C) s += __expf(v4 - m);
        if (i5 < C) s += __expf(v5 - m);

        float xt = 0.0f;
        xt += (i0 == c) ? v0 : 0.0f;
        xt += (i1 == c) ? v1 : 0.0f;
        xt += (i2 == c) ? v2 : 0.0f;
        xt += (i3 == c) ? v3 : 0.0f;
        xt += (i4 == c) ? v4 : 0.0f;
        xt += (i5 == c) ? v5 : 0.0f;

#pragma unroll
        for (int o = 8; o; o >>= 1) {
            s  += __shfl_xor(s, o);
            xt += __shfl_xor(xt, o);
        }

        if (l == 0 && valid) {
            float ce = m + __logf(s) - xt;
            lossc[row] = (c > 0) ? 0.0f : ce;
            if (c > 0) pos_acc += ce;
        }
    }
    if (pos_acc != 0.0f) atomicAdd(&posce[b], pos_acc);
}

// ---------------- Kernel C: hard negative mining via bit-bisection select ----------------
__global__ __launch_bounds__(256) void hnm_kernel(
    const float* __restrict__ lossc, const int* __restrict__ num_pos,
    const float* __restrict__ posce, int D,
    float* __restrict__ hnm)
{
    const int b = blockIdx.x;
    const int tid = threadIdx.x;
    __shared__ unsigned s_bits[DMAX];
    __shared__ int s_cnt[4];
    __shared__ float s_sf[4];

    for (int d = tid; d < D; d += blockDim.x)
        s_bits[d] = __float_as_uint(lossc[(size_t)b * D + d]);
    const int k = min(num_pos[b] * 3, D);
    __syncthreads();

    // largest uint T with count(bits >= T) >= k  ->  T = bits of k-th largest value
    unsigned T = 0;
    for (int bit = 30; bit >= 0; --bit) {   // finite non-negative floats: bit31=0
        unsigned cand = T | (1u << bit);
        int cnt = 0;
        for (int d = tid; d < D; d += blockDim.x) cnt += (s_bits[d] >= cand) ? 1 : 0;
        for (int o = 32; o; o >>= 1) cnt += __shfl_down(cnt, o);
        if ((tid & 63) == 0) s_cnt[tid >> 6] = cnt;
        __syncthreads();
        int tot = s_cnt[0] + s_cnt[1] + s_cnt[2] + s_cnt[3];
        if (tot >= k) T = cand;
        __syncthreads();
    }

    // sum of top-k values = sum(v > Vk) + (k - count(v > Vk)) * Vk   (tie-agnostic)
    int cgt = 0; float sgt = 0.0f;
    for (int d = tid; d < D; d += blockDim.x) {
        unsigned v = s_bits[d];
        if (v > T) { ++cgt; sgt += __uint_as_float(v); }
    }
    for (int o = 32; o; o >>= 1) { cgt += __shfl_down(cgt, o); sgt += __shfl_down(sgt, o); }
    if ((tid & 63) == 0) { s_cnt[tid >> 6] = cgt; s_sf[tid >> 6] = sgt; }
    __syncthreads();
    if (tid == 0) {
        int C_gt = s_cnt[0] + s_cnt[1] + s_cnt[2] + s_cnt[3];
        float S_gt = s_sf[0] + s_sf[1] + s_sf[2] + s_sf[3];
        hnm[b] = posce[b] + S_gt + (float)(k - C_gt) * __uint_as_float(T);
    }
}

// ---------------- Kernel D: finalize ----------------
__global__ void finalize_kernel(
    const int* __restrict__ num_pos, const float* __restrict__ loss_l_part,
    const float* __restrict__ hnm, int B, float* __restrict__ out)
{
    int lane = threadIdx.x;
    int np = 0; float ll = 0.0f, lc = 0.0f;
    for (int b = lane; b < B; b += 64) {
        np += num_pos[b]; ll += loss_l_part[b]; lc += hnm[b];
    }
    for (int o = 32; o; o >>= 1) {
        np += __shfl_down(np, o); ll += __shfl_down(ll, o); lc += __shfl_down(lc, o);
    }
    if (lane == 0) {
        float N = (float)np;
        out[0] = ll / N;
        out[1] = lc / N;
    }
}

extern "C" void kernel_launch(void* const* d_in, const int* in_sizes, int n_in,
                              void* d_out, int out_size, void* d_ws, size_t ws_size,
                              hipStream_t stream) {
    const float* loc     = (const float*)d_in[0];
    const float* conf    = (const float*)d_in[1];
    const float* dbox    = (const float*)d_in[2];
    const float* targets = (const float*)d_in[3];

    const int D = in_sizes[2] / 4;               // 8732
    const int B = in_sizes[0] / (D * 4);         // 64
    const int C = in_sizes[1] / (B * D);         // 81

    char* p = (char*)d_ws;
    int*   conf_t      = (int*)p;   p += (size_t)B * D * sizeof(int);
    float* lossc       = (float*)p; p += (size_t)B * D * sizeof(float);
    int*   num_pos     = (int*)p;   p += (size_t)B * sizeof(int);
    float* loss_l_part = (float*)p; p += (size_t)B * sizeof(float);
    float* posce       = (float*)p; p += (size_t)B * sizeof(float);
    float* hnm         = (float*)p; p += (size_t)B * sizeof(float);

    match_kernel<8><<<B, 256, 0, stream>>>(loc, dbox, targets, D,
                                           conf_t, num_pos, loss_l_part, posce);
    ce_kernel<<<dim3(32, B), 256, 0, stream>>>(conf, conf_t, D, C, lossc, posce);
    hnm_kernel<<<B, 256, 0, stream>>>(lossc, num_pos, posce, D, hnm);
    finalize_kernel<<<1, 64, 0, stream>>>(num_pos, loss_l_part, hnm, B, (float*)d_out);
}